// Round 1
// baseline (167.076 us; speedup 1.0000x reference)
//
#include <hip/hip_runtime.h>
#include <math.h>

#define DD 32
#define MM 16
#define TROW 72   // tbl row: t[32] | it[32] | cj[8]

__device__ __forceinline__ void load8f4(const float* __restrict__ p, float* r) {
    const float4* q = (const float4*)p;
#pragma unroll
    for (int i = 0; i < 8; ++i) {
        float4 v = q[i];
        r[4*i+0] = v.x; r[4*i+1] = v.y; r[4*i+2] = v.z; r[4*i+3] = v.w;
    }
}

// One thread per (item, dim): 1.6M threads instead of 50K.
// tbl[i*72 + 0..31]  = t_i[d]  = sum_e W_bil[d][e] * item_e[i][e]
// tbl[i*72 + 32..63] = item_e[i][d]          (copy, avoids 2nd gather stream in main)
// tbl[i*72 + 64..71] = c_i[j]  = sum_d W1[j][64+d] * item_e[i][d]
__global__ void precompute_item(const float* __restrict__ item_table,
                                const float* __restrict__ W_bil,
                                const float* __restrict__ W1,
                                float* __restrict__ tbl, int NI) {
    int g = blockIdx.x * blockDim.x + threadIdx.x;
    if (g >= NI * DD) return;
    int i = g >> 5;
    int d = g & (DD - 1);
    float it[DD];
    load8f4(item_table + (size_t)i * DD, it);   // same-address across 32 lanes -> broadcast
    const float* w = W_bil + d * DD;
    float s0 = 0.f, s1 = 0.f, s2 = 0.f, s3 = 0.f;
#pragma unroll
    for (int e = 0; e < DD; e += 4) {
        s0 = fmaf(w[e+0], it[e+0], s0);
        s1 = fmaf(w[e+1], it[e+1], s1);
        s2 = fmaf(w[e+2], it[e+2], s2);
        s3 = fmaf(w[e+3], it[e+3], s3);
    }
    float* o = tbl + (size_t)i * TROW;
    o[d]      = (s0 + s1) + (s2 + s3);
    o[DD + d] = it[d];
    if (d < 8) {
        const float* w1 = W1 + d * 96 + 64;
        float c0 = 0.f, c1 = 0.f, c2 = 0.f, c3 = 0.f;
#pragma unroll
        for (int e = 0; e < DD; e += 4) {
            c0 = fmaf(w1[e+0], it[e+0], c0);
            c1 = fmaf(w1[e+1], it[e+1], c1);
            c2 = fmaf(w1[e+2], it[e+2], c2);
            c3 = fmaf(w1[e+3], it[e+3], c3);
        }
        o[64 + d] = (c0 + c1) + (c2 + c3);
    }
}

// One member: 4-way partial dot (dep chain 32*4cy -> ~8*4cy) then fin accumulate.
__device__ __forceinline__ void member1(const float* __restrict__ ut, int id,
                                        const float* __restrict__ t, float bb,
                                        float* __restrict__ fin) {
    float me[DD];
    load8f4(ut + (size_t)id * DD, me);
    float s0 = 0.f, s1 = 0.f, s2 = 0.f, s3 = 0.f;
#pragma unroll
    for (int d = 0; d < DD; d += 4) {
        s0 = fmaf(me[d+0], t[d+0], s0);
        s1 = fmaf(me[d+1], t[d+1], s1);
        s2 = fmaf(me[d+2], t[d+2], s2);
        s3 = fmaf(me[d+3], t[d+3], s3);
    }
    float s = ((s0 + s1) + (s2 + s3)) + bb;
#pragma unroll
    for (int d = 0; d < DD; ++d) fin[d] = fmaf(s, me[d], fin[d]);
}

// Two members: all 16 float4 loads issued up front so B's L2 latency hides
// under A's compute (compiler inserts per-consumer vmcnt waits).
__device__ __forceinline__ void member2(const float* __restrict__ ut, int ia, int ib,
                                        const float* __restrict__ t, float bb,
                                        float* __restrict__ fin) {
    float ma[DD], mb[DD];
    load8f4(ut + (size_t)ia * DD, ma);
    load8f4(ut + (size_t)ib * DD, mb);
    float a0 = 0.f, a1 = 0.f, a2 = 0.f, a3 = 0.f;
    float c0 = 0.f, c1 = 0.f, c2 = 0.f, c3 = 0.f;
#pragma unroll
    for (int d = 0; d < DD; d += 4) {
        a0 = fmaf(ma[d+0], t[d+0], a0);
        a1 = fmaf(ma[d+1], t[d+1], a1);
        a2 = fmaf(ma[d+2], t[d+2], a2);
        a3 = fmaf(ma[d+3], t[d+3], a3);
        c0 = fmaf(mb[d+0], t[d+0], c0);
        c1 = fmaf(mb[d+1], t[d+1], c1);
        c2 = fmaf(mb[d+2], t[d+2], c2);
        c3 = fmaf(mb[d+3], t[d+3], c3);
    }
    float sa = ((a0 + a1) + (a2 + a3)) + bb;
    float sb = ((c0 + c1) + (c2 + c3)) + bb;
#pragma unroll
    for (int d = 0; d < DD; ++d) fin[d] = fmaf(sa, ma[d], fin[d]);
#pragma unroll
    for (int d = 0; d < DD; ++d) fin[d] = fmaf(sb, mb[d], fin[d]);
}

// __launch_bounds__(256): without it the backend budgets VGPRs for a 1024-thread
// block (cap ~128); with it we can hold the 64-float two-member staging in regs
// (~165 VGPR -> 3 waves/SIMD resident; grid only supplies 4/SIMD anyway).
template <bool USE_TBL>
__global__ __launch_bounds__(256)
void bilinear_main(const int* __restrict__ item_inputs,
                   const int* __restrict__ member_ids,
                   const unsigned char* __restrict__ member_mask,
                   const float* __restrict__ user_table,
                   const float* __restrict__ item_table,
                   const float* __restrict__ tbl,
                   const float* __restrict__ W_bil,
                   const float* __restrict__ b_bil,
                   const float* __restrict__ W1,
                   const float* __restrict__ b1v,
                   const float* __restrict__ W2,
                   const float* __restrict__ b2v,
                   float* __restrict__ out, int Btot) {
    int b = blockIdx.x * blockDim.x + threadIdx.x;
    if (b >= Btot) return;

    int item = item_inputs[b];

    // Prefix mask -> length via popcount of 0x01 bytes (16B aligned).
    uint4 mv = *(const uint4*)(member_mask + (size_t)b * MM);
    int len = __popc(mv.x & 0x01010101u) + __popc(mv.y & 0x01010101u) +
              __popc(mv.z & 0x01010101u) + __popc(mv.w & 0x01010101u);

    int ids[MM];
    {
        const int4* mp = (const int4*)(member_ids + (size_t)b * MM);
#pragma unroll
        for (int q = 0; q < 4; ++q) {
            int4 v = mp[q];
            ids[4*q+0] = v.x; ids[4*q+1] = v.y; ids[4*q+2] = v.z; ids[4*q+3] = v.w;
        }
    }

    float t[DD];
    const float* tb = nullptr;
    if (USE_TBL) {
        tb = tbl + (size_t)item * TROW;
        load8f4(tb, t);
    } else {
        float it0[DD];
        load8f4(item_table + (size_t)item * DD, it0);
#pragma unroll 4
        for (int d = 0; d < DD; ++d) {
            float s = 0.f;
#pragma unroll
            for (int e = 0; e < DD; ++e) s = fmaf(W_bil[d * DD + e], it0[e], s);
            t[d] = s;
        }
    }

    float bb = b_bil[0];
    float fin[DD];
#pragma unroll
    for (int d = 0; d < DD; ++d) fin[d] = 0.f;

    // Member loop, unrolled by 2 (paired loads in flight).
    int m = 0;
    for (; m + 2 <= len; m += 2)
        member2(user_table, ids[m], ids[m+1], t, bb, fin);
    if (m < len)
        member1(user_table, ids[m], t, bb, fin);

    // Epilogue: it + cj.
    float it[DD];
    float cj[8];
    if (USE_TBL) {
        load8f4(tb + DD, it);
        float4 q0 = *(const float4*)(tb + 64);
        float4 q1 = *(const float4*)(tb + 68);
        cj[0] = q0.x; cj[1] = q0.y; cj[2] = q0.z; cj[3] = q0.w;
        cj[4] = q1.x; cj[5] = q1.y; cj[6] = q1.z; cj[7] = q1.w;
    } else {
        load8f4(item_table + (size_t)item * DD, it);
#pragma unroll
        for (int j = 0; j < 8; ++j) {
            float s = 0.f;
#pragma unroll
            for (int d = 0; d < DD; ++d) s = fmaf(W1[j * 96 + 64 + d], it[d], s);
            cj[j] = s;
        }
    }

    // MLP: h_j = relu(c_j + b1_j + sum_d W1[j,d]*(f*i)[d] + W1[j,32+d]*f[d])
    float h[8];
#pragma unroll
    for (int j = 0; j < 8; ++j) h[j] = cj[j] + b1v[j];
#pragma unroll
    for (int d = 0; d < DD; ++d) {
        float f = fin[d];
        float p = f * it[d];
#pragma unroll
        for (int j = 0; j < 8; ++j) {
            h[j] = fmaf(W1[j * 96 + d], p, h[j]);
            h[j] = fmaf(W1[j * 96 + 32 + d], f, h[j]);
        }
    }
    float z = b2v[0];
#pragma unroll
    for (int j = 0; j < 8; ++j) {
        float hv = h[j] > 0.f ? h[j] : 0.f;
        z = fmaf(W2[j], hv, z);
    }
    out[b] = 1.f / (1.f + __expf(-z));
}

extern "C" void kernel_launch(void* const* d_in, const int* in_sizes, int n_in,
                              void* d_out, int out_size, void* d_ws, size_t ws_size,
                              hipStream_t stream) {
    const int*           item_inputs = (const int*)d_in[0];
    const int*           member_ids  = (const int*)d_in[1];
    const unsigned char* member_mask = (const unsigned char*)d_in[2];
    const float*         user_table  = (const float*)d_in[3];
    const float*         item_table  = (const float*)d_in[4];
    const float*         W_bil       = (const float*)d_in[5];
    const float*         b_bil       = (const float*)d_in[6];
    const float*         W1          = (const float*)d_in[7];
    const float*         b1          = (const float*)d_in[8];
    const float*         W2          = (const float*)d_in[9];
    const float*         b2          = (const float*)d_in[10];
    float* out = (float*)d_out;

    int Btot = in_sizes[0];
    int NI   = in_sizes[4] / DD;

    bool use_tbl = ws_size >= (size_t)NI * TROW * sizeof(float);
    int blk = 256;
    if (use_tbl) {
        float* tbl = (float*)d_ws;
        precompute_item<<<(NI * DD + blk - 1) / blk, blk, 0, stream>>>(item_table, W_bil, W1, tbl, NI);
        bilinear_main<true><<<(Btot + blk - 1) / blk, blk, 0, stream>>>(
            item_inputs, member_ids, member_mask, user_table, item_table, tbl,
            W_bil, b_bil, W1, b1, W2, b2, out, Btot);
    } else {
        bilinear_main<false><<<(Btot + blk - 1) / blk, blk, 0, stream>>>(
            item_inputs, member_ids, member_mask, user_table, item_table, nullptr,
            W_bil, b_bil, W1, b1, W2, b2, out, Btot);
    }
}